// Round 1
// baseline (2997.078 us; speedup 1.0000x reference)
//
#include <hip/hip_runtime.h>

#define NVEH 8192
#define NT   512

// fast sigmoid/tanh via hardware exp2 + rcp (fp32, ~1 ulp rcp; tolerance is 0.104 absmax)
__device__ __forceinline__ float fsig(float x) {
    float e = __builtin_amdgcn_exp2f(-1.44269504f * x);
    return __builtin_amdgcn_rcpf(1.0f + e);
}
__device__ __forceinline__ float ftanh(float x) {
    // tanh(x) = 2*sigmoid(2x) - 1
    float e = __builtin_amdgcn_exp2f(-2.88539008f * x);
    return 2.0f * __builtin_amdgcn_rcpf(1.0f + e) - 1.0f;
}

// One wave (64 threads) per block; 4 lanes per vehicle -> 16 vehicles/block.
// Lane r of a quad owns LSTM units [5r, 5r+5) -- all four gates -- so the
// cell update is lane-local. h is regathered via 20 intra-quad shuffles.
__global__ __launch_bounds__(64) void lstm_scan_kernel(
    const float* __restrict__ lead,   // (8192, 512, 12)
    const float* __restrict__ traj,   // (8192, 512)
    const float* __restrict__ hidden, // (2, 8192, 20)
    const float* __restrict__ W_k,    // (12, 80)
    const float* __restrict__ W_r,    // (20, 80)
    const float* __restrict__ b_l,    // (80,)
    const float* __restrict__ W_d,    // (20, 10)
    const float* __restrict__ b_d,    // (10,)
    const float* __restrict__ W_lc,   // (10, 3)
    const float* __restrict__ b_lc,   // (3,)
    float* __restrict__ out_lc,       // (8192, 512, 3)
    float* __restrict__ out_h,        // (8192, 20)
    float* __restrict__ out_c)        // (8192, 20)
{
    // Transposed/permuted weights: column c = 4*unit + gate  (orig col = gate*20 + unit).
    // Row stride 36 floats = 144 B (16B aligned -> ds_read_b128; wave sees 4 distinct
    // broadcast addresses; 720%32=16 -> 2-way bank aliasing, free per m136).
    __shared__ float sWT[80 * 36];
    __shared__ float sB[80];
    __shared__ float sWdT[10 * 20];   // sWdT[u][k] = W_d[k][u]
    __shared__ float sBd[16];
    __shared__ float sWlcT[3 * 12];   // sWlcT[j][u] = W_lc[u][j]
    __shared__ float sBlc[4];

    const int tid = threadIdx.x;

    for (int idx = tid; idx < 80 * 32; idx += 64) {
        int c = idx >> 5, k = idx & 31;
        int u = c >> 2, g = c & 3;
        int col = g * 20 + u;
        float w = (k < 12) ? W_k[k * 80 + col] : W_r[(k - 12) * 80 + col];
        sWT[c * 36 + k] = w;
    }
    for (int c = tid; c < 80; c += 64) {
        int u = c >> 2, g = c & 3;
        sB[c] = b_l[g * 20 + u];
    }
    for (int idx = tid; idx < 200; idx += 64) {
        int u = idx / 20, k = idx % 20;
        sWdT[u * 20 + k] = W_d[k * 10 + u];
    }
    if (tid < 10) sBd[tid] = b_d[tid];
    if (tid < 30) { int j = tid / 10, u = tid % 10; sWlcT[j * 12 + u] = W_lc[u * 3 + j]; }
    if (tid < 3)  sBlc[tid] = b_lc[tid];
    __syncthreads();

    const int vid  = blockIdx.x * 16 + (tid >> 2);
    const int r    = tid & 3;
    const int col0 = 20 * r;

    float c_st[5];
    float hn[5];
    float xh[32];   // [0..11] = preprocessed x, [12..31] = full h

    {
        const float* h0 = hidden + (size_t)vid * 20;
        const float* c0 = hidden + (size_t)NVEH * 20 + (size_t)vid * 20;
        #pragma unroll
        for (int j = 0; j < 20; ++j) xh[12 + j] = h0[j];
        #pragma unroll
        for (int j = 0; j < 5; ++j) c_st[j] = c0[5 * r + j];
    }

    const float* lf_base  = lead + (size_t)vid * (NT * 12);
    const float* pos_base = traj + (size_t)vid * NT;
    float*       lc_base  = out_lc + (size_t)vid * (NT * 3);

    // load + preprocess x for t=0
    float raw[12];
    float pos;
    {
        const float4* p = (const float4*)lf_base;
        float4 a = p[0], b = p[1], c4 = p[2];
        raw[0] = a.x; raw[1] = a.y; raw[2]  = a.z;  raw[3]  = a.w;
        raw[4] = b.x; raw[5] = b.y; raw[6]  = b.z;  raw[7]  = b.w;
        raw[8] = c4.x; raw[9] = c4.y; raw[10] = c4.z; raw[11] = c4.w;
        pos = pos_base[0];
    }
    {
        const float inv_hd = 0.01f, inv_v = 0.025f;
        #pragma unroll
        for (int j = 0; j < 3; ++j) xh[j]     = (raw[j] - pos) * inv_hd;
        #pragma unroll
        for (int j = 0; j < 3; ++j) xh[3 + j] = (pos - raw[3 + j]) * inv_hd;
        #pragma unroll
        for (int j = 0; j < 6; ++j) xh[6 + j] = raw[6 + j] * inv_v;
        #pragma unroll
        for (int j = 0; j < 12; ++j) { float v = xh[j]; xh[j] = (v == v) ? v : 1.0f; }
    }

    for (int t = 0; t < NT; ++t) {
        // ---- prefetch next timestep's raw inputs (hides HBM latency at 1 wave/SIMD)
        const int tn = (t + 1 < NT) ? (t + 1) : t;
        float nraw[12], npos;
        {
            const float4* p = (const float4*)(lf_base + (size_t)tn * 12);
            float4 a = p[0], b = p[1], c4 = p[2];
            nraw[0] = a.x; nraw[1] = a.y; nraw[2]  = a.z;  nraw[3]  = a.w;
            nraw[4] = b.x; nraw[5] = b.y; nraw[6]  = b.z;  nraw[7]  = b.w;
            nraw[8] = c4.x; nraw[9] = c4.y; nraw[10] = c4.z; nraw[11] = c4.w;
            npos = pos_base[tn];
        }

        // ---- z = [x|h] @ W + b for this lane's 20 columns (640 FMA, ds_read_b128 weights)
        float z[20];
        #pragma unroll
        for (int i = 0; i < 20; ++i) z[i] = sB[col0 + i];
        #pragma unroll
        for (int i = 0; i < 20; ++i) {
            const float* w = &sWT[(col0 + i) * 36];
            float acc = z[i];
            #pragma unroll
            for (int k = 0; k < 32; ++k) acc = fmaf(w[k], xh[k], acc);
            z[i] = acc;
        }

        // ---- gates + cell update (lane-local for this lane's 5 units)
        #pragma unroll
        for (int j = 0; j < 5; ++j) {
            float si = fsig(z[4 * j + 0]);
            float sf = fsig(z[4 * j + 1]);
            float tg = ftanh(z[4 * j + 2]);
            float so = fsig(z[4 * j + 3]);
            float cn = sf * c_st[j] + si * tg;
            c_st[j] = cn;
            hn[j]   = so * ftanh(cn);
        }

        // ---- regather full h (intra-quad shuffles)
        #pragma unroll
        for (int s = 0; s < 4; ++s)
            #pragma unroll
            for (int j = 0; j < 5; ++j)
                xh[12 + s * 5 + j] = __shfl(hn[j], s, 4);

        // ---- head: d = relu(h@W_d + b_d); lc = d@W_lc + b_lc (redundant per quad lane)
        float d[10];
        #pragma unroll
        for (int u = 0; u < 10; ++u) {
            float acc = sBd[u];
            const float* w = &sWdT[u * 20];
            #pragma unroll
            for (int k = 0; k < 20; ++k) acc = fmaf(w[k], xh[12 + k], acc);
            d[u] = fmaxf(acc, 0.0f);
        }
        float lc0 = sBlc[0], lc1 = sBlc[1], lc2 = sBlc[2];
        #pragma unroll
        for (int u = 0; u < 10; ++u) {
            lc0 = fmaf(sWlcT[0 * 12 + u], d[u], lc0);
            lc1 = fmaf(sWlcT[1 * 12 + u], d[u], lc1);
            lc2 = fmaf(sWlcT[2 * 12 + u], d[u], lc2);
        }
        if (r == 0) {
            float* o = lc_base + (size_t)t * 3;
            o[0] = lc0; o[1] = lc1; o[2] = lc2;
        }

        // ---- preprocess prefetched x into xh[0..11] for next step
        {
            const float inv_hd = 0.01f, inv_v = 0.025f;
            #pragma unroll
            for (int j = 0; j < 3; ++j) xh[j]     = (nraw[j] - npos) * inv_hd;
            #pragma unroll
            for (int j = 0; j < 3; ++j) xh[3 + j] = (npos - nraw[3 + j]) * inv_hd;
            #pragma unroll
            for (int j = 0; j < 6; ++j) xh[6 + j] = nraw[6 + j] * inv_v;
            #pragma unroll
            for (int j = 0; j < 12; ++j) { float v = xh[j]; xh[j] = (v == v) ? v : 1.0f; }
        }
    }

    // ---- final h, c
    #pragma unroll
    for (int j = 0; j < 5; ++j) {
        out_h[(size_t)vid * 20 + 5 * r + j] = hn[j];
        out_c[(size_t)vid * 20 + 5 * r + j] = c_st[j];
    }
}

extern "C" void kernel_launch(void* const* d_in, const int* in_sizes, int n_in,
                              void* d_out, int out_size, void* d_ws, size_t ws_size,
                              hipStream_t stream) {
    const float* lead   = (const float*)d_in[0];
    const float* traj   = (const float*)d_in[1];
    const float* hidden = (const float*)d_in[2];
    const float* W_k    = (const float*)d_in[3];
    const float* W_r    = (const float*)d_in[4];
    const float* b_l    = (const float*)d_in[5];
    const float* W_d    = (const float*)d_in[6];
    const float* b_d    = (const float*)d_in[7];
    const float* W_lc   = (const float*)d_in[8];
    const float* b_lc   = (const float*)d_in[9];

    float* out    = (float*)d_out;
    float* out_tt = out;                                   // true_traj  (8192*512)
    float* out_lc = out + (size_t)NVEH * NT;               // pred_lc    (8192*512*3)
    float* out_h  = out_lc + (size_t)NVEH * NT * 3;        // h          (8192*20)
    float* out_c  = out_h + (size_t)NVEH * 20;             // c          (8192*20)

    // output 0 is just the input trajectory passed through
    hipMemcpyAsync(out_tt, traj, (size_t)NVEH * NT * sizeof(float),
                   hipMemcpyDeviceToDevice, stream);

    lstm_scan_kernel<<<dim3(NVEH / 16), dim3(64), 0, stream>>>(
        lead, traj, hidden, W_k, W_r, b_l, W_d, b_d, W_lc, b_lc,
        out_lc, out_h, out_c);
}

// Round 2
// 816.430 us; speedup vs baseline: 3.6710x; 3.6710x over previous
//
#include <hip/hip_runtime.h>

#define NVEH 8192
#define NT   512

typedef short bf16x8 __attribute__((ext_vector_type(8)));
typedef float f32x4  __attribute__((ext_vector_type(4)));

__device__ __forceinline__ float fsig(float x) {
    float e = __builtin_amdgcn_exp2f(-1.44269504f * x);
    return __builtin_amdgcn_rcpf(1.0f + e);
}
__device__ __forceinline__ float ftanh(float x) {
    float e = __builtin_amdgcn_exp2f(-2.88539008f * x);
    return 2.0f * __builtin_amdgcn_rcpf(1.0f + e) - 1.0f;
}
// f32 -> bf16 bit pattern, round-to-nearest-even
__device__ __forceinline__ unsigned short f2bf(float f) {
    union { float f; unsigned u; } v; v.f = f;
    unsigned r = v.u + 0x7fff + ((v.u >> 16) & 1);
    return (unsigned short)(r >> 16);
}

// One wave per block; wave handles 16 vehicles via MFMA 16x16x32 bf16.
//   A = W^T permuted (col p = 4u+g), 5 tiles of 16 rows, resident in VGPRs.
//   B = xh (K=32: x[0..11], h[0..19]) as bf16 in LDS, 1 ds_read_b128/lane.
//   C = bias (free accumulate-init).
// D layout (col=lane&15, row=quad*4+reg): lane (q, v) gets gates reg=0..3 of
// units u=4t+q, t=0..4, vehicle v -> cell update is lane-local.
__global__ __launch_bounds__(64) void lstm_scan_kernel(
    const float* __restrict__ lead,   // (8192, 512, 12)
    const float* __restrict__ traj,   // (8192, 512)
    const float* __restrict__ hidden, // (2, 8192, 20)
    const float* __restrict__ W_k,    // (12, 80)
    const float* __restrict__ W_r,    // (20, 80)
    const float* __restrict__ b_l,    // (80,)
    const float* __restrict__ W_d,    // (20, 10)
    const float* __restrict__ b_d,    // (10,)
    const float* __restrict__ W_lc,   // (10, 3)
    const float* __restrict__ b_lc,   // (3,)
    float* __restrict__ out_lc,       // (8192, 512, 3)
    float* __restrict__ out_h,        // (8192, 20)
    float* __restrict__ out_c)        // (8192, 20)
{
    // bf16 buffers, row stride 40 ushorts (80 B): b128 reads stay 16B-aligned,
    // 20v mod 32 gives only 2-way bank aliasing (free).
    __shared__ alignas(16) unsigned short xhb[16 * 40]; // k=0..11 x, 12..31 h
    __shared__ alignas(16) unsigned short hb [16 * 40]; // k=0..19 h, rest 0
    __shared__ alignas(16) unsigned short db [16 * 40]; // k=0..15 d, rest 0

    const int lane = threadIdx.x;
    const int q    = lane >> 4;
    const int v    = lane & 15;
    const int gv   = blockIdx.x * 16 + v;

    for (int i = lane; i < 640; i += 64) { xhb[i] = 0; hb[i] = 0; db[i] = 0; }

    // ---- weights -> register fragments (one-time, L2-broadcast across waves)
    bf16x8 aW[5]; f32x4 cB[5];
    #pragma unroll
    for (int tt = 0; tt < 5; ++tt) {
        #pragma unroll
        for (int j = 0; j < 8; ++j) {
            int k = q * 8 + j;
            int p = 16 * tt + v;          // A row m = lane&15
            int u = p >> 2, g = p & 3;
            int col = g * 20 + u;
            float w = (k < 12) ? W_k[k * 80 + col] : W_r[(k - 12) * 80 + col];
            aW[tt][j] = (short)f2bf(w);
        }
        #pragma unroll
        for (int reg = 0; reg < 4; ++reg)
            cB[tt][reg] = b_l[reg * 20 + 4 * tt + q];
    }
    bf16x8 aH; f32x4 cD;
    #pragma unroll
    for (int j = 0; j < 8; ++j) {
        int k = q * 8 + j;
        aH[j] = (v < 10 && k < 20) ? (short)f2bf(W_d[k * 10 + v]) : (short)0;
    }
    #pragma unroll
    for (int reg = 0; reg < 4; ++reg) {
        int m = 4 * q + reg;
        cD[reg] = (m < 10) ? b_d[m] : 0.0f;
    }
    bf16x8 aL; f32x4 cL;
    #pragma unroll
    for (int j = 0; j < 8; ++j) {
        int k = q * 8 + j;
        aL[j] = (v < 3 && k < 10) ? (short)f2bf(W_lc[k * 3 + v]) : (short)0;
    }
    #pragma unroll
    for (int reg = 0; reg < 4; ++reg) {
        int m = 4 * q + reg;
        cL[reg] = (m < 3) ? b_lc[m] : 0.0f;
    }

    // ---- state: lane owns units u = 4t+q of vehicle v
    float cst[5], h32[5];
    #pragma unroll
    for (int tt = 0; tt < 5; ++tt) {
        int u = 4 * tt + q;
        h32[tt] = hidden[(size_t)gv * 20 + u];
        cst[tt] = hidden[(size_t)NVEH * 20 + (size_t)gv * 20 + u];
    }
    #pragma unroll
    for (int tt = 0; tt < 5; ++tt) {
        int u = 4 * tt + q;
        unsigned short hu = f2bf(h32[tt]);
        xhb[v * 40 + 12 + u] = hu;
    }

    // ---- per-lane x-preprocess coefficients: x_e = raw_e*Ac + pos*Bc
    float Ac[4], Bc[4];
    #pragma unroll
    for (int i = 0; i < 4; ++i) {
        int e = 4 * q + i;
        if (e < 3)      { Ac[i] =  0.01f;  Bc[i] = -0.01f; }
        else if (e < 6) { Ac[i] = -0.01f;  Bc[i] =  0.01f; }
        else            { Ac[i] =  0.025f; Bc[i] =  0.0f;  }
    }

    const float* lf = lead + (size_t)gv * NT * 12;
    const float* ps = traj + (size_t)gv * NT;
    float* lcout    = out_lc + (size_t)gv * NT * 3;

    // x(0) synchronous
    float4 r0 = make_float4(0.f, 0.f, 0.f, 0.f);
    float  p0 = 0.f;
    if (q < 3) r0 = *(const float4*)(lf + q * 4);
    if (q < 2) p0 = ps[0];
    if (q < 3) {
        float xv[4] = { r0.x, r0.y, r0.z, r0.w };
        #pragma unroll
        for (int i = 0; i < 4; ++i) {
            float x = fmaf(xv[i], Ac[i], p0 * Bc[i]);
            xv[i] = (x == x) ? x : 1.0f;
        }
        uint2 val;
        val.x = (unsigned)f2bf(xv[0]) | ((unsigned)f2bf(xv[1]) << 16);
        val.y = (unsigned)f2bf(xv[2]) | ((unsigned)f2bf(xv[3]) << 16);
        *(uint2*)&xhb[v * 40 + q * 4] = val;
    }

    // depth-2 prefetch: rA = raw(t+1), rB = raw(t+2)
    float4 rA = make_float4(0.f,0.f,0.f,0.f), rB = make_float4(0.f,0.f,0.f,0.f);
    float  pA = 0.f, pB = 0.f;
    if (q < 3) { rA = *(const float4*)(lf + 12 * 1 + q * 4);
                 rB = *(const float4*)(lf + 12 * 2 + q * 4); }
    if (q < 2) { pA = ps[1]; pB = ps[2]; }

    __syncthreads();   // one real barrier pre-loop only

    for (int t = 0; t < NT; ++t) {
        // (A) B-fragment: xh_t, one b128 per lane
        bf16x8 bx = *(const bf16x8*)&xhb[v * 40 + q * 8];

        // (C) z = W^T·xh + b : 5 independent MFMAs
        f32x4 z[5];
        #pragma unroll
        for (int tt = 0; tt < 5; ++tt)
            z[tt] = __builtin_amdgcn_mfma_f32_16x16x32_bf16(aW[tt], bx, cB[tt], 0, 0, 0);

        // (D) gates: reg 0..3 = i,f,c,o (lane-local)
        #pragma unroll
        for (int tt = 0; tt < 5; ++tt) {
            float si = fsig(z[tt][0]);
            float sf = fsig(z[tt][1]);
            float tg = ftanh(z[tt][2]);
            float so = fsig(z[tt][3]);
            float cn = fmaf(sf, cst[tt], si * tg);
            cst[tt] = cn;
            h32[tt] = so * ftanh(cn);
        }

        // (E_h) publish h_t for next-step B-frag and for the head
        #pragma unroll
        for (int tt = 0; tt < 5; ++tt) {
            int u = 4 * tt + q;
            unsigned short hu = f2bf(h32[tt]);
            xhb[v * 40 + 12 + u] = hu;
            hb [v * 40 + u]      = hu;
        }
        __builtin_amdgcn_wave_barrier();

        // (G) head MFMA 1: d = relu(Wd^T·h + bd)
        bf16x8 bh = *(const bf16x8*)&hb[v * 40 + q * 8];
        f32x4 d = __builtin_amdgcn_mfma_f32_16x16x32_bf16(aH, bh, cD, 0, 0, 0);
        #pragma unroll
        for (int reg = 0; reg < 4; ++reg)
            db[v * 40 + 4 * q + reg] = f2bf(fmaxf(d[reg], 0.0f));
        __builtin_amdgcn_wave_barrier();

        // (I) head MFMA 2: lc = Wlc^T·d + blc ; store by quad-0 lanes
        bf16x8 bd2 = *(const bf16x8*)&db[v * 40 + q * 8];
        f32x4 lcv = __builtin_amdgcn_mfma_f32_16x16x32_bf16(aL, bd2, cL, 0, 0, 0);
        if (q == 0) {
            float* o = lcout + (size_t)t * 3;
            o[0] = lcv[0]; o[1] = lcv[1]; o[2] = lcv[2];
        }

        // (E_x) write x(t+1) from prefetched regs (loaded ~2 iters ago)
        if (q < 3) {
            float xv[4] = { rA.x, rA.y, rA.z, rA.w };
            #pragma unroll
            for (int i = 0; i < 4; ++i) {
                float x = fmaf(xv[i], Ac[i], pA * Bc[i]);
                xv[i] = (x == x) ? x : 1.0f;
            }
            uint2 val;
            val.x = (unsigned)f2bf(xv[0]) | ((unsigned)f2bf(xv[1]) << 16);
            val.y = (unsigned)f2bf(xv[2]) | ((unsigned)f2bf(xv[3]) << 16);
            *(uint2*)&xhb[v * 40 + q * 4] = val;
        }

        // rotate prefetch, issue raw(t+3)
        rA = rB; pA = pB;
        int tn = (t + 3 < NT) ? (t + 3) : (NT - 1);
        if (q < 3) rB = *(const float4*)(lf + 12 * tn + q * 4);
        if (q < 2) pB = ps[tn];
        __builtin_amdgcn_wave_barrier();
    }

    // ---- final h, c (fp32 state kept in registers)
    #pragma unroll
    for (int tt = 0; tt < 5; ++tt) {
        int u = 4 * tt + q;
        out_h[(size_t)gv * 20 + u] = h32[tt];
        out_c[(size_t)gv * 20 + u] = cst[tt];
    }
}

extern "C" void kernel_launch(void* const* d_in, const int* in_sizes, int n_in,
                              void* d_out, int out_size, void* d_ws, size_t ws_size,
                              hipStream_t stream) {
    const float* lead   = (const float*)d_in[0];
    const float* traj   = (const float*)d_in[1];
    const float* hidden = (const float*)d_in[2];
    const float* W_k    = (const float*)d_in[3];
    const float* W_r    = (const float*)d_in[4];
    const float* b_l    = (const float*)d_in[5];
    const float* W_d    = (const float*)d_in[6];
    const float* b_d    = (const float*)d_in[7];
    const float* W_lc   = (const float*)d_in[8];
    const float* b_lc   = (const float*)d_in[9];

    float* out    = (float*)d_out;
    float* out_tt = out;                                   // true_traj  (8192*512)
    float* out_lc = out + (size_t)NVEH * NT;               // pred_lc    (8192*512*3)
    float* out_h  = out_lc + (size_t)NVEH * NT * 3;        // h          (8192*20)
    float* out_c  = out_h + (size_t)NVEH * 20;             // c          (8192*20)

    hipMemcpyAsync(out_tt, traj, (size_t)NVEH * NT * sizeof(float),
                   hipMemcpyDeviceToDevice, stream);

    lstm_scan_kernel<<<dim3(NVEH / 16), dim3(64), 0, stream>>>(
        lead, traj, hidden, W_k, W_r, b_l, W_d, b_d, W_lc, b_lc,
        out_lc, out_h, out_c);
}

// Round 3
// 797.632 us; speedup vs baseline: 3.7575x; 1.0236x over previous
//
#include <hip/hip_runtime.h>

#define NVEH 8192
#define NT   512

typedef short bf16x8 __attribute__((ext_vector_type(8)));
typedef float f32x4  __attribute__((ext_vector_type(4)));

__device__ __forceinline__ float fsig(float x) {
    float e = __builtin_amdgcn_exp2f(-1.44269504f * x);
    return __builtin_amdgcn_rcpf(1.0f + e);
}
__device__ __forceinline__ float ftanh(float x) {
    float e = __builtin_amdgcn_exp2f(-2.88539008f * x);
    return 2.0f * __builtin_amdgcn_rcpf(1.0f + e) - 1.0f;
}
__device__ __forceinline__ unsigned short f2bf(float f) {
    union { float f; unsigned u; } vv; vv.f = f;
    unsigned r = vv.u + 0x7fff + ((vv.u >> 16) & 1);
    return (unsigned short)(r >> 16);
}

// One wave per block, 16 vehicles/wave via 16x16x32 bf16 MFMA.
// Per step: ONE LDS round-trip (h publish + gather into next B-frag); x moves
// via register shuffles; head MFMA reuses the same B-frag with A=[0|W_d];
// lc reduced with shfl_xor butterflies; 1 predicated 12B store/step.
__global__ __launch_bounds__(64) void lstm_scan_kernel(
    const float* __restrict__ lead, const float* __restrict__ traj,
    const float* __restrict__ hidden,
    const float* __restrict__ W_k, const float* __restrict__ W_r,
    const float* __restrict__ b_l, const float* __restrict__ W_d,
    const float* __restrict__ b_d, const float* __restrict__ W_lc,
    const float* __restrict__ b_lc,
    float* __restrict__ out_lc, float* __restrict__ out_h, float* __restrict__ out_c)
{
    // h row per vehicle: 80 B (u16 idx: u<4 -> u, else u+4) so the b64/b128
    // gather reads are 8/16B aligned; 80B row stride -> 2-way banks (free).
    __shared__ alignas(16) unsigned short hrow[16 * 40];

    const int lane = threadIdx.x;
    const int q    = lane >> 4;
    const int v    = lane & 15;
    const int gv   = blockIdx.x * 16 + v;

    // ---- z-MFMA fragments: A = W^T permuted (col p = 4u+g), bias as C
    bf16x8 aW[5]; f32x4 cB[5];
    #pragma unroll
    for (int tt = 0; tt < 5; ++tt) {
        #pragma unroll
        for (int j = 0; j < 8; ++j) {
            int k = q * 8 + j;
            int p = 16 * tt + v;
            int u = p >> 2, g = p & 3;
            int col = g * 20 + u;
            float w = (k < 12) ? W_k[k * 80 + col] : W_r[(k - 12) * 80 + col];
            aW[tt][j] = (short)f2bf(w);
        }
        #pragma unroll
        for (int reg = 0; reg < 4; ++reg)
            cB[tt][reg] = b_l[reg * 20 + 4 * tt + q];
    }
    // ---- head MFMA: A[m][k] = W_d[k-12][m] for k>=12, 0 for k<12 (ignores x slots)
    bf16x8 aH; f32x4 cD;
    #pragma unroll
    for (int j = 0; j < 8; ++j) {
        int k = q * 8 + j;
        aH[j] = (v < 10 && k >= 12) ? (short)f2bf(W_d[(k - 12) * 10 + v]) : (short)0;
    }
    #pragma unroll
    for (int reg = 0; reg < 4; ++reg) {
        int m = 4 * q + reg;
        cD[reg] = (m < 10) ? b_d[m] : 0.0f;
    }
    // ---- lc stage consts: lane (q,v) holds W_lc rows 4q..4q+3
    float wlc[4][3]; float pb0[3];
    #pragma unroll
    for (int reg = 0; reg < 4; ++reg) {
        int m = 4 * q + reg;
        #pragma unroll
        for (int j = 0; j < 3; ++j) wlc[reg][j] = (m < 10) ? W_lc[m * 3 + j] : 0.0f;
    }
    #pragma unroll
    for (int j = 0; j < 3; ++j) pb0[j] = (q == 0) ? b_lc[j] : 0.0f;

    // ---- state
    float h32[5], cst[5];
    #pragma unroll
    for (int tt = 0; tt < 5; ++tt) {
        int u = 4 * tt + q;
        h32[tt] = hidden[(size_t)gv * 20 + u];
        cst[tt] = hidden[(size_t)NVEH * 20 + (size_t)gv * 20 + u];
    }
    // publish h(init)
    #pragma unroll
    for (int tt = 0; tt < 5; ++tt) {
        int u = 4 * tt + q;
        int idx = (tt == 0) ? u : u + 4;
        hrow[v * 40 + idx] = f2bf(h32[tt]);
    }

    // ---- per-lane x coefficients (elements 4q..4q+3): x = raw*Ac + pos*Bc
    float Ac[4], Bc[4];
    #pragma unroll
    for (int i = 0; i < 4; ++i) {
        int e = 4 * q + i;
        if (e < 3)      { Ac[i] =  0.01f;  Bc[i] = -0.01f; }
        else if (e < 6) { Ac[i] = -0.01f;  Bc[i] =  0.01f; }
        else            { Ac[i] =  0.025f; Bc[i] =  0.0f;  }
    }

    const float* lf = lead + (size_t)gv * NT * 12;
    const float* ps = traj + (size_t)gv * NT;
    float* lcout    = out_lc + (size_t)gv * NT * 3;

    // ---- x(0) -> packs
    float4 r0 = make_float4(0.f,0.f,0.f,0.f); float p0s = 0.f;
    if (q < 3) r0 = *(const float4*)(lf + q * 4);
    if (q < 2) p0s = ps[0];
    unsigned pk0 = 0, pk1 = 0;
    if (q < 3) {
        float xv[4] = { r0.x, r0.y, r0.z, r0.w };
        #pragma unroll
        for (int i = 0; i < 4; ++i) {
            float x = fmaf(xv[i], Ac[i], p0s * Bc[i]);
            xv[i] = (x == x) ? x : 1.0f;
        }
        pk0 = (unsigned)f2bf(xv[0]) | ((unsigned)f2bf(xv[1]) << 16);
        pk1 = (unsigned)f2bf(xv[2]) | ((unsigned)f2bf(xv[3]) << 16);
    }
    __builtin_amdgcn_wave_barrier();

    // ---- assemble bx(0): q0=[x0..7], q1=[x8..11|h0..3], q2=[h4..11], q3=[h12..19]
    bf16x8 bx;
    {
        unsigned s0 = __shfl_down(pk0, 16), s1 = __shfl_down(pk1, 16);
        uint2 hA = make_uint2(0, 0); uint4 hB = make_uint4(0, 0, 0, 0);
        if (q == 1) hA = *(const uint2*)&hrow[v * 40];
        if (q >= 2) hB = *(const uint4*)&hrow[v * 40 + (q == 2 ? 8 : 16)];
        unsigned dw0 = (q == 0) ? pk0 : (q == 1) ? s0   : hB.x;
        unsigned dw1 = (q == 0) ? pk1 : (q == 1) ? s1   : hB.y;
        unsigned dw2 = (q == 0) ? s0  : (q == 1) ? hA.x : hB.z;
        unsigned dw3 = (q == 0) ? s1  : (q == 1) ? hA.y : hB.w;
        uint4 tmp = make_uint4(dw0, dw1, dw2, dw3);
        bx = *(bf16x8*)&tmp;
    }

    // ---- depth-2 prefetch
    float4 rA = make_float4(0.f,0.f,0.f,0.f), rB = make_float4(0.f,0.f,0.f,0.f);
    float pA = 0.f, pB = 0.f;
    if (q < 3) { rA = *(const float4*)(lf + 12 * 1 + q * 4);
                 rB = *(const float4*)(lf + 12 * 2 + q * 4); }
    if (q < 2) { pA = ps[1]; pB = ps[2]; }

    for (int t = 0; t < NT; ++t) {
        // z = W^T * [x_t | h_{t-1}] + b
        f32x4 z[5];
        #pragma unroll
        for (int tt = 0; tt < 5; ++tt)
            z[tt] = __builtin_amdgcn_mfma_f32_16x16x32_bf16(aW[tt], bx, cB[tt], 0, 0, 0);

        // gates (reg 0..3 = i,f,g,o), lane-local cell update
        #pragma unroll
        for (int tt = 0; tt < 5; ++tt) {
            float si = fsig(z[tt][0]);
            float sf = fsig(z[tt][1]);
            float tg = ftanh(z[tt][2]);
            float so = fsig(z[tt][3]);
            float cn = fmaf(sf, cst[tt], si * tg);
            cst[tt] = cn;
            h32[tt] = so * ftanh(cn);
        }

        // publish h_t
        #pragma unroll
        for (int tt = 0; tt < 5; ++tt) {
            int u = 4 * tt + q;
            int idx = (tt == 0) ? u : u + 4;
            hrow[v * 40 + idx] = f2bf(h32[tt]);
        }

        // x(t+1) packs from prefetched regs
        if (q < 3) {
            float xv[4] = { rA.x, rA.y, rA.z, rA.w };
            #pragma unroll
            for (int i = 0; i < 4; ++i) {
                float x = fmaf(xv[i], Ac[i], pA * Bc[i]);
                xv[i] = (x == x) ? x : 1.0f;
            }
            pk0 = (unsigned)f2bf(xv[0]) | ((unsigned)f2bf(xv[1]) << 16);
            pk1 = (unsigned)f2bf(xv[2]) | ((unsigned)f2bf(xv[3]) << 16);
        }
        __builtin_amdgcn_wave_barrier();

        // gather next B-frag: bxn = [x_{t+1} | h_t]
        bf16x8 bxn;
        {
            unsigned s0 = __shfl_down(pk0, 16), s1 = __shfl_down(pk1, 16);
            uint2 hA = make_uint2(0, 0); uint4 hB = make_uint4(0, 0, 0, 0);
            if (q == 1) hA = *(const uint2*)&hrow[v * 40];
            if (q >= 2) hB = *(const uint4*)&hrow[v * 40 + (q == 2 ? 8 : 16)];
            unsigned dw0 = (q == 0) ? pk0 : (q == 1) ? s0   : hB.x;
            unsigned dw1 = (q == 0) ? pk1 : (q == 1) ? s1   : hB.y;
            unsigned dw2 = (q == 0) ? s0  : (q == 1) ? hA.x : hB.z;
            unsigned dw3 = (q == 0) ? s1  : (q == 1) ? hA.y : hB.w;
            uint4 tmp = make_uint4(dw0, dw1, dw2, dw3);
            bxn = *(bf16x8*)&tmp;
        }

        // head: d = relu(h_t @ W_d + b_d) via MFMA on bxn (A zeros x-cols)
        f32x4 d = __builtin_amdgcn_mfma_f32_16x16x32_bf16(aH, bxn, cD, 0, 0, 0);
        float dr[4];
        #pragma unroll
        for (int reg = 0; reg < 4; ++reg) dr[reg] = fmaxf(d[reg], 0.0f);

        // lc partials + quad butterfly reduce (lanes v, v+16, v+32, v+48)
        float p[3];
        #pragma unroll
        for (int j = 0; j < 3; ++j) {
            float acc = pb0[j];
            #pragma unroll
            for (int reg = 0; reg < 4; ++reg) acc = fmaf(dr[reg], wlc[reg][j], acc);
            acc += __shfl_xor(acc, 16);
            acc += __shfl_xor(acc, 32);
            p[j] = acc;
        }

        // one predicated 12B store per step (quad round-robin)
        if (q == (t & 3)) {
            float* o = lcout + (size_t)t * 3;
            *(float2*)o = make_float2(p[0], p[1]);
            o[2] = p[2];
        }

        bx = bxn;

        // rotate prefetch
        rA = rB; pA = pB;
        int tn = (t + 3 < NT) ? (t + 3) : (NT - 1);
        if (q < 3) rB = *(const float4*)(lf + 12 * tn + q * 4);
        if (q < 2) pB = ps[tn];
        __builtin_amdgcn_wave_barrier();
    }

    #pragma unroll
    for (int tt = 0; tt < 5; ++tt) {
        int u = 4 * tt + q;
        out_h[(size_t)gv * 20 + u] = h32[tt];
        out_c[(size_t)gv * 20 + u] = cst[tt];
    }
}

extern "C" void kernel_launch(void* const* d_in, const int* in_sizes, int n_in,
                              void* d_out, int out_size, void* d_ws, size_t ws_size,
                              hipStream_t stream) {
    const float* lead   = (const float*)d_in[0];
    const float* traj   = (const float*)d_in[1];
    const float* hidden = (const float*)d_in[2];
    const float* W_k    = (const float*)d_in[3];
    const float* W_r    = (const float*)d_in[4];
    const float* b_l    = (const float*)d_in[5];
    const float* W_d    = (const float*)d_in[6];
    const float* b_d    = (const float*)d_in[7];
    const float* W_lc   = (const float*)d_in[8];
    const float* b_lc   = (const float*)d_in[9];

    float* out    = (float*)d_out;
    float* out_tt = out;
    float* out_lc = out + (size_t)NVEH * NT;
    float* out_h  = out_lc + (size_t)NVEH * NT * 3;
    float* out_c  = out_h + (size_t)NVEH * 20;

    hipMemcpyAsync(out_tt, traj, (size_t)NVEH * NT * sizeof(float),
                   hipMemcpyDeviceToDevice, stream);

    lstm_scan_kernel<<<dim3(NVEH / 16), dim3(64), 0, stream>>>(
        lead, traj, hidden, W_k, W_r, b_l, W_d, b_d, W_lc, b_lc,
        out_lc, out_h, out_c);
}